// Round 1
// 132.235 us; speedup vs baseline: 1.0141x; 1.0141x over previous
//
#include <hip/hip_runtime.h>
#include <hip/hip_bf16.h>

#define CIN    32
#define NPIX   4096   // 64*64 spatial positions
#define DIM    64     // attention channels
#define LOG2E  1.4426950408889634f

#if __has_builtin(__builtin_amdgcn_exp2f)
#define EXP2(x) __builtin_amdgcn_exp2f(x)
#else
#define EXP2(x) exp2f(x)
#endif

typedef float  f32x4 __attribute__((ext_vector_type(4)));
typedef short  s16x8 __attribute__((ext_vector_type(8)));   // 8 bf16 = one K=32 MFMA A/B fragment
typedef short  s16x4 __attribute__((ext_vector_type(4)));   // 4 bf16 = one K=16 MFMA A/B fragment

// K=16 MFMA: B-frag layout (k=quad*4+j, col=l16) matches the 16x16 C-layout
// (row=quad*4+r, col=l16) exactly -> P^T feeds PV straight from registers.
__device__ __forceinline__ f32x4 mfma16(s16x4 a, s16x4 b, f32x4 c) {
#if __has_builtin(__builtin_amdgcn_mfma_f32_16x16x16bf16_1k)
    return __builtin_amdgcn_mfma_f32_16x16x16bf16_1k(a, b, c, 0, 0, 0);
#elif __has_builtin(__builtin_amdgcn_mfma_f32_16x16x16_bf16)
    return __builtin_amdgcn_mfma_f32_16x16x16_bf16(a, b, c, 0, 0, 0);
#else
    f32x4 d;
    asm("v_mfma_f32_16x16x16_bf16 %0, %1, %2, %3" : "=v"(d) : "v"(a), "v"(b), "v"(c));
    return d;
#endif
}

// K global layout (K=32 A-frag order), per batch: [tile16(256)][kb2(2)][l16(16)][quad(4)][j(8)]
// V global layout (K=16 A-frag order of V^T), per batch:
//   [step(128)][ct(4)][lane(64)][nt(2)][j(4)]  (8B chunks; lane=quad'*16+l16;
//   element = V[key=step*32+nt*16+quad'*4+j][ch=ct*16+l16])
// Q row-major (B, N, 64), PRE-SCALED by log2(e). No softmax shift anywhere.

// ---------------------------------------------------------------------------
// Kernel A: QKV projection. Q/K unchanged; V emitted in V^T K=16 A-frag order.
// ---------------------------------------------------------------------------
__global__ __launch_bounds__(256) void qkv_proj(
    const float* __restrict__ x,
    const float* __restrict__ wq, const float* __restrict__ bq,
    const float* __restrict__ wk, const float* __restrict__ bk,
    const float* __restrict__ wv, const float* __restrict__ bv,
    __hip_bfloat16* __restrict__ qb, __hip_bfloat16* __restrict__ kb,
    __hip_bfloat16* __restrict__ vb)
{
    __shared__ float Xs[CIN][64];        // [c_in][pixel]
    __shared__ float wT[3][CIN][DIM];    // [mat][c_in][c_out]; wT[0] pre-scaled

    const int tid = threadIdx.x;
    const int b   = blockIdx.y;
    const int bx  = blockIdx.x;
    const int n0  = bx * 64;

    for (int i = tid; i < 3 * CIN * DIM; i += 256) {
        int m = i >> 11, r = i & 2047, c = r >> 6, o = r & 63;
        const float* wsrc = (m == 0) ? wq : (m == 1) ? wk : wv;
        float wv0 = wsrc[o * CIN + c];
        wT[m][c][o] = (m == 0) ? wv0 * LOG2E : wv0;
    }
    for (int i = tid * 4; i < CIN * 64; i += 1024) {
        int c = i >> 6, p = i & 63;
        *(f32x4*)&Xs[c][p] = *(const f32x4*)&x[((size_t)b * CIN + c) * NPIX + n0 + p];
    }
    __syncthreads();

    const int w    = tid >> 6;
    const int lane = tid & 63;
    const int l16  = lane >> 2;
    const int quad = lane & 3;

    const int T  = bx * 4 + w;
    const int px = T * 16 + l16;

    float aq[2][8], ak[2][8];
    #pragma unroll
    for (int kb2 = 0; kb2 < 2; kb2++) {
        f32x4 bq0 = *(const f32x4*)&bq[kb2 * 32 + quad * 8];
        f32x4 bq1 = *(const f32x4*)&bq[kb2 * 32 + quad * 8 + 4];
        f32x4 bk0 = *(const f32x4*)&bk[kb2 * 32 + quad * 8];
        f32x4 bk1 = *(const f32x4*)&bk[kb2 * 32 + quad * 8 + 4];
        #pragma unroll
        for (int j = 0; j < 4; j++) {
            aq[kb2][j] = bq0[j] * LOG2E; aq[kb2][j + 4] = bq1[j] * LOG2E;
            ak[kb2][j] = bk0[j];         ak[kb2][j + 4] = bk1[j];
        }
    }
    #pragma unroll 8
    for (int c = 0; c < CIN; c++) {
        const float xc = Xs[c][w * 16 + l16];
        #pragma unroll
        for (int kb2 = 0; kb2 < 2; kb2++) {
            f32x4 q0 = *(const f32x4*)&wT[0][c][kb2 * 32 + quad * 8];
            f32x4 q1 = *(const f32x4*)&wT[0][c][kb2 * 32 + quad * 8 + 4];
            f32x4 k0 = *(const f32x4*)&wT[1][c][kb2 * 32 + quad * 8];
            f32x4 k1 = *(const f32x4*)&wT[1][c][kb2 * 32 + quad * 8 + 4];
            #pragma unroll
            for (int j = 0; j < 4; j++) {
                aq[kb2][j]     += xc * q0[j];
                aq[kb2][j + 4] += xc * q1[j];
                ak[kb2][j]     += xc * k0[j];
                ak[kb2][j + 4] += xc * k1[j];
            }
        }
    }
    #pragma unroll
    for (int kb2 = 0; kb2 < 2; kb2++) {
        union { s16x8 v; __hip_bfloat16 h[8]; } pq, pk;
        #pragma unroll
        for (int j = 0; j < 8; j++) {
            pq.h[j] = __float2bfloat16(aq[kb2][j]);
            pk.h[j] = __float2bfloat16(ak[kb2][j]);
        }
        *(s16x8*)(qb + ((size_t)b * NPIX + px) * DIM + kb2 * 32 + quad * 8) = pq.v;
        const size_t koff =
            ((((size_t)(b * 256 + T) * 2 + kb2) * 16 + l16) * 4 + quad) * 8;
        *(s16x8*)(kb + koff) = pk.v;
    }

    const int ch = w * 16 + l16;
    float av[2][8];
    {
        const float bvc = bv[ch];
        #pragma unroll
        for (int kh = 0; kh < 2; kh++)
            #pragma unroll
            for (int j = 0; j < 8; j++) av[kh][j] = bvc;
    }
    #pragma unroll 8
    for (int c = 0; c < CIN; c++) {
        const float wvc = wT[2][c][ch];
        f32x4 x0 = *(const f32x4*)&Xs[c][quad * 8];
        f32x4 x1 = *(const f32x4*)&Xs[c][quad * 8 + 4];
        f32x4 x2 = *(const f32x4*)&Xs[c][32 + quad * 8];
        f32x4 x3 = *(const f32x4*)&Xs[c][32 + quad * 8 + 4];
        #pragma unroll
        for (int j = 0; j < 4; j++) {
            av[0][j]     += x0[j] * wvc;
            av[0][j + 4] += x1[j] * wvc;
            av[1][j]     += x2[j] * wvc;
            av[1][j + 4] += x3[j] * wvc;
        }
    }
    // av[kh][jj] = V[pixel = kh*32 + quad*8 + jj][ch].  Emit V^T K=16 A-frag order:
    // key kk32 = quad*8+jj -> nt = quad>>1, quad' = (quad&1)*2 + (jj>>2), j = jj&3.
    #pragma unroll
    for (int kh = 0; kh < 2; kh++) {
        #pragma unroll
        for (int h = 0; h < 2; h++) {
            union { unsigned long long u; __hip_bfloat16 hh[4]; } pv;
            #pragma unroll
            for (int j = 0; j < 4; j++) pv.hh[j] = __float2bfloat16(av[kh][h * 4 + j]);
            const int lanep = ((quad & 1) * 2 + h) * 16 + l16;
            const size_t chunk =
                (((size_t)(b * 128 + bx * 2 + kh) * 4 + w) * 64 + lanep) * 2 + (quad >> 1);
            *(unsigned long long*)(vb + chunk * 4) = pv.u;
        }
    }
}

// ---------------------------------------------------------------------------
// Kernel B: fused flash attention + out-proj + residual. Barrier-free loop,
// NO LDS in the main loop: S^T C-layout == K=16 B-frag layout, so
// exp2+pack feeds O^T = V^T P^T (mfma16) straight from registers.
// Row-sum l via ones-A mfma16 (all 4 rows of D identical).
// ---------------------------------------------------------------------------
__global__ __launch_bounds__(256, 2) void attn_fused(
    const __hip_bfloat16* __restrict__ qb,
    const __hip_bfloat16* __restrict__ kbf,
    const __hip_bfloat16* __restrict__ vbf,
    const float* __restrict__ wo, const float* __restrict__ bo,
    const float* __restrict__ x, float* __restrict__ y)
{
    __shared__ __align__(16) float RED[3][64][66];   // [wave-1][ch][qrow] 50688 B
    __shared__ float LRED[3][64];                    // row-sums            768 B

    const int tid  = threadIdx.x;
    const int kq   = tid >> 6;          // wave id = key quarter
    const int lane = tid & 63;
    const int quad = lane >> 4, l16 = lane & 15;
    const int b    = blockIdx.x;        // batch -> XCD affinity (lin%8 = b)
    const int row0 = blockIdx.y * 64;

    // Q fragments (B-operand for S^T, K=32) — registers, whole kernel
    s16x8 qf[4][2];
    #pragma unroll
    for (int mt = 0; mt < 4; mt++)
        #pragma unroll
        for (int kb2 = 0; kb2 < 2; kb2++)
            qf[mt][kb2] = *(const s16x8*)(qb
                + ((size_t)b * NPIX + row0 + mt * 16 + l16) * DIM + kb2 * 32 + quad * 8);

    const f32x4 zero4 = {0.f, 0.f, 0.f, 0.f};
    f32x4 o[4][4];     // o[mt][ct][r] = O^T[ch=ct*16+quad*4+r][qrow=mt*16+l16]
    #pragma unroll
    for (int mt = 0; mt < 4; mt++)
        #pragma unroll
        for (int ct = 0; ct < 4; ct++) o[mt][ct] = zero4;
    f32x4 ol[4] = {zero4, zero4, zero4, zero4};   // l[qrow] replicated in r

    s16x4 ones;
    #pragma unroll
    for (int j = 0; j < 4; j++) ones[j] = (short)0x3F80;   // bf16 1.0

    // direct-global fragment pointers: wave's quarter = 128KB K + 128KB V
    const char* kp = (const char*)kbf + (size_t)b * 524288 + kq * 131072
                     + (l16 * 4 + quad) * 16;
    const char* vp = (const char*)vbf + (size_t)b * 524288 + kq * 131072
                     + lane * 16;

    s16x8 ckA[4], cvA[4], ckB[4], cvB[4];
    #pragma unroll
    for (int i = 0; i < 4; i++) {
        ckA[i] = *(const s16x8*)(kp + i * 1024);
        cvA[i] = *(const s16x8*)(vp + i * 1024);
    }

    // one 32-key step: consume CUR, prefetch next tile into NXT
    auto step = [&](s16x8 (&curK)[4], s16x8 (&curV)[4],
                    s16x8 (&nxtK)[4], s16x8 (&nxtV)[4]) {
        kp += 4096; vp += 4096;   // final prefetch overreads 4KB inside ws -- harmless
        // S^T = K(A) x Q(B): lane holds key=nt*16+quad*4+r, qrow=mt*16+l16
        f32x4 st[2][4];
        #pragma unroll
        for (int nt = 0; nt < 2; nt++)
            #pragma unroll
            for (int mt = 0; mt < 4; mt++) {
                st[nt][mt] = __builtin_amdgcn_mfma_f32_16x16x32_bf16(
                    curK[nt * 2 + 0], qf[mt][0], zero4, 0, 0, 0);
                st[nt][mt] = __builtin_amdgcn_mfma_f32_16x16x32_bf16(
                    curK[nt * 2 + 1], qf[mt][1], st[nt][mt], 0, 0, 0);
            }
        #pragma unroll
        for (int i = 0; i < 4; i++) nxtK[i] = *(const s16x8*)(kp + i * 1024);

        // P^T = exp2(S^T); truncation-pack straight into K=16 B-frags
        s16x4 pb[2][4];
        #pragma unroll
        for (int nt = 0; nt < 2; nt++)
            #pragma unroll
            for (int mt = 0; mt < 4; mt++) {
                f32x4 p = st[nt][mt];
                #pragma unroll
                for (int r = 0; r < 4; r++) p[r] = EXP2(p[r]);
                union { unsigned int d[2]; s16x4 v; } pk;
                pk.d[0] = (__float_as_uint(p[1]) & 0xffff0000u)
                        | (__float_as_uint(p[0]) >> 16);
                pk.d[1] = (__float_as_uint(p[3]) & 0xffff0000u)
                        | (__float_as_uint(p[2]) >> 16);
                pb[nt][mt] = pk.v;
            }

        // O^T += V^T P^T (mfma16, zero cross-lane traffic); l += ones x P^T
        #pragma unroll
        for (int ct = 0; ct < 4; ct++) {
            s16x4 vlo = __builtin_shufflevector(curV[ct], curV[ct], 0, 1, 2, 3);
            s16x4 vhi = __builtin_shufflevector(curV[ct], curV[ct], 4, 5, 6, 7);
            #pragma unroll
            for (int mt = 0; mt < 4; mt++) {
                o[mt][ct] = mfma16(vlo, pb[0][mt], o[mt][ct]);
                o[mt][ct] = mfma16(vhi, pb[1][mt], o[mt][ct]);
            }
        }
        #pragma unroll
        for (int mt = 0; mt < 4; mt++) {
            ol[mt] = mfma16(ones, pb[0][mt], ol[mt]);
            ol[mt] = mfma16(ones, pb[1][mt], ol[mt]);
        }
        #pragma unroll
        for (int i = 0; i < 4; i++) nxtV[i] = *(const s16x8*)(vp + i * 1024);
    };

    for (int it = 0; it < 16; it++) {   // 32 key-steps, ping-pong
        step(ckA, cvA, ckB, cvB);
        step(ckB, cvB, ckA, cvA);
    }

    // ---- cross-quarter reduction (epilogue-only LDS) ----
    if (kq != 0) {
        #pragma unroll
        for (int mt = 0; mt < 4; mt++) {
            #pragma unroll
            for (int ct = 0; ct < 4; ct++)
                #pragma unroll
                for (int r = 0; r < 4; r++)
                    RED[kq - 1][ct * 16 + quad * 4 + r][mt * 16 + l16] = o[mt][ct][r];
            if (quad == 0)
                LRED[kq - 1][mt * 16 + l16] = ol[mt][0];
        }
    }
    __syncthreads();

    if (kq == 0) {
        #pragma unroll
        for (int reg = 0; reg < 3; reg++)
            #pragma unroll
            for (int mt = 0; mt < 4; mt++) {
                ol[mt][0] += LRED[reg][mt * 16 + l16];    // broadcast read
                #pragma unroll
                for (int ct = 0; ct < 4; ct++)
                    #pragma unroll
                    for (int r = 0; r < 4; r++)
                        o[mt][ct][r] += RED[reg][ct * 16 + quad * 4 + r][mt * 16 + l16];
            }

        // normalize -> bf16 B-frags directly from registers (no LDS staging)
        s16x4 pvo[4][4];
        #pragma unroll
        for (int mt = 0; mt < 4; mt++) {
            const float inv = 1.0f / ol[mt][0];
            #pragma unroll
            for (int ct = 0; ct < 4; ct++) {
                union { s16x4 v; __hip_bfloat16 h[4]; } pk;
                #pragma unroll
                for (int r = 0; r < 4; r++)
                    pk.h[r] = __float2bfloat16(o[mt][ct][r] * inv);
                pvo[mt][ct] = pk.v;
            }
        }

        // wo A-frags (K=16): A[row=out=nt*16+l16][k=ch=ct*16+quad*4+j]
        s16x4 aw[2][4];
        #pragma unroll
        for (int nt = 0; nt < 2; nt++)
            #pragma unroll
            for (int ct = 0; ct < 4; ct++) {
                f32x4 w4 = *(const f32x4*)(wo + (size_t)(nt * 16 + l16) * DIM
                                           + ct * 16 + quad * 4);
                union { s16x4 v; __hip_bfloat16 h[4]; } wf;
                #pragma unroll
                for (int j = 0; j < 4; j++) wf.h[j] = __float2bfloat16(w4[j]);
                aw[nt][ct] = wf.v;
            }

        // Y^T[out][qrow] = wo x ONorm^T
        f32x4 d2[4][2];
        #pragma unroll
        for (int mt = 0; mt < 4; mt++)
            #pragma unroll
            for (int nt = 0; nt < 2; nt++) d2[mt][nt] = zero4;
        #pragma unroll
        for (int ct = 0; ct < 4; ct++)
            #pragma unroll
            for (int nt = 0; nt < 2; nt++)
                #pragma unroll
                for (int mt = 0; mt < 4; mt++)
                    d2[mt][nt] = mfma16(aw[nt][ct], pvo[mt][ct], d2[mt][nt]);

        // bias + residual + store y (B, 32, 4096) fp32
        #pragma unroll
        for (int nt = 0; nt < 2; nt++)
            #pragma unroll
            for (int r = 0; r < 4; r++) {
                const int out = nt * 16 + quad * 4 + r;
                const float bias = bo[out];
                #pragma unroll
                for (int mt = 0; mt < 4; mt++) {
                    const int row = row0 + mt * 16 + l16;
                    const size_t xi = ((size_t)b * CIN + out) * NPIX + row;
                    y[xi] = d2[mt][nt][r] + bias + x[xi];
                }
            }
    }
}

// ---------------------------------------------------------------------------
extern "C" void kernel_launch(void* const* d_in, const int* in_sizes, int n_in,
                              void* d_out, int out_size, void* d_ws, size_t ws_size,
                              hipStream_t stream)
{
    const float* x  = (const float*)d_in[0];
    const float* wq = (const float*)d_in[1];
    const float* bq = (const float*)d_in[2];
    const float* wk = (const float*)d_in[3];
    const float* bk = (const float*)d_in[4];
    const float* wv = (const float*)d_in[5];
    const float* bv = (const float*)d_in[6];
    const float* wo = (const float*)d_in[7];
    const float* bo = (const float*)d_in[8];
    float* y = (float*)d_out;

    // workspace: qb 4MB (row-major, log2e-scaled) | kb 4MB | vb 4MB (V^T frag order)
    char* ws = (char*)d_ws;
    __hip_bfloat16* qb = (__hip_bfloat16*)(ws);
    __hip_bfloat16* kb = (__hip_bfloat16*)(ws + (4u << 20));
    __hip_bfloat16* vb = (__hip_bfloat16*)(ws + (8u << 20));

    qkv_proj<<<dim3(64, 8), dim3(256), 0, stream>>>(x, wq, bq, wk, bk, wv, bv, qb, kb, vb);
    attn_fused<<<dim3(8, 64), dim3(256), 0, stream>>>(qb, kb, vb, wo, bo, x, y);
}